// Round 6
// baseline (73.254 us; speedup 1.0000x reference)
//
#include <hip/hip_runtime.h>

// DataTermLayer: per-pixel optical-flow data-term update.
// Inputs (float32, each B*H*W = 16*1024*1024):
//   d_in[0]=I1, d_in[1]=I2, d_in[2]=u, d_in[3]=v
// Output: d_out = [u_next (N floats) | v_next (N floats)]
//
// Faithful-to-reference: grad_x := dy (vertical diff), grad_y := dx
// (horizontal diff) — the Python source swaps them.
//
// R6: kill the 9.3M-cycle LDS bank conflicts found in R5.
//  (a) Gradients from coalesced GLOBAL vector loads again (lines are
//      L1/L2-hot from the fill) — deletes 12 stride-4-lane LDS reads
//      per thread that were a deterministic 8-way conflict.
//  (b) XOR-swizzle LDS columns: store lx at lx ^ ((lx>>5)&3). Lane
//      addresses 4l -> 4l ^ (l>>3) cover all 32 banks 2x per wave
//      (2-way aliasing is free). Bijective within each 32-col block,
//      stays in [0,LW). Gathers compute the swizzled index per column.

#define ALPHA 0.15f
#define IMG_H 1024
#define IMG_W 1024
#define TW 128
#define TH 8
#define HALO 4
#define LW (TW + 9)   // 137: halo 4 left, 5 right (x1 = x0+1)
#define LH (TH + 9)   // 17:  halo 4 up,   5 down  (y1 = y0+1)

typedef float f32x4 __attribute__((ext_vector_type(4)));

__device__ __forceinline__ int swz(int lx) {
    return lx ^ ((lx >> 5) & 3);
}

__global__ __launch_bounds__(256) void dataterm_kernel(
        const float* __restrict__ I1,
        const float* __restrict__ I2,
        const float* __restrict__ u,
        const float* __restrict__ v,
        float* __restrict__ out_u,
        float* __restrict__ out_v) {
    const int W = IMG_W, H = IMG_H;
    const int t   = threadIdx.x;
    const int tx0 = blockIdx.x * TW;
    const int ty0 = blockIdx.y * TH;
    const int b   = blockIdx.z;

    const float* __restrict__ I1b = I1 + (size_t)b * (size_t)(H * W);

    __shared__ float S[LH * LW];

    // --- cooperative clamped tile fill (coalesced reads, swizzled stores) ---
    for (int f = t; f < LH * LW; f += 256) {
        int ly = f / LW;
        int lx = f - ly * LW;
        int gy = min(max(ty0 - HALO + ly, 0), H - 1);
        int gx = min(max(tx0 - HALO + lx, 0), W - 1);
        S[ly * LW + swz(lx)] = I1b[gy * W + gx];
    }
    __syncthreads();

    // thread -> 4 consecutive pixels of one row
    const int r  = t >> 5;           // row within tile, 0..7
    const int cb = (t & 31) << 2;    // col base within tile, 0..124
    const int h  = ty0 + r;
    const int wb = tx0 + cb;
    const int p  = (b * H + h) * W + wb;

    // --- gradients from global (L1/L2-hot after the fill) ---
    const float* rowc = I1b + h * W + wb;
    f32x4 c4 = *(const f32x4*)rowc;
    bool lastcol = (wb + 4 > W - 1);
    float c4r = lastcol ? 0.0f : rowc[4];
    f32x4 d4 = (h < H - 1) ? *(const f32x4*)(rowc + W) : c4;

    float gy4[4] = { d4.x - c4.x, d4.y - c4.y, d4.z - c4.z, d4.w - c4.w };
    float gx4[4] = { c4.y - c4.x, c4.z - c4.y, c4.w - c4.z,
                     lastcol ? 0.0f : (c4r - c4.w) };

    f32x4 u4  = *(const f32x4*)(u + p);
    f32x4 v4  = *(const f32x4*)(v + p);
    f32x4 i24 = *(const f32x4*)(I2 + p);

    float uu[4] = { u4.x, u4.y, u4.z, u4.w };
    float vv[4] = { v4.x, v4.y, v4.z, v4.w };
    float i2[4] = { i24.x, i24.y, i24.z, i24.w };
    float ru[4], rv[4];

    #pragma unroll
    for (int i = 0; i < 4; ++i) {
        float x = (float)(wb + i) + 0.5f * uu[i];
        float y = (float)h        + 0.5f * vv[i];

        float x0f = floorf(x);
        float y0f = floorf(y);
        float wx1 = x - x0f;
        float wx0 = 1.0f - wx1;
        float wy1 = y - y0f;
        float wy0 = 1.0f - wy1;

        int x0 = (int)x0f, y0 = (int)y0f;
        int x1 = x0 + 1,   y1 = y0 + 1;

        float vx0 = (x0 >= 0 && x0 <= W - 1) ? 1.0f : 0.0f;
        float vx1 = (x1 >= 0 && x1 <= W - 1) ? 1.0f : 0.0f;
        float vy0 = (y0 >= 0 && y0 <= H - 1) ? 1.0f : 0.0f;
        float vy1 = (y1 >= 0 && y1 <= H - 1) ? 1.0f : 0.0f;

        int lx0 = x0 - tx0 + HALO;
        int ly0 = y0 - ty0 + HALO;

        float g00, g01, g10, g11;
        if ((unsigned)lx0 <= (unsigned)(LW - 2) &&
            (unsigned)ly0 <= (unsigned)(LH - 2)) {
            // in-tile (the always case): gather from swizzled LDS
            int a0 = ly0 * LW;
            int s0 = swz(lx0);
            int s1 = swz(lx0 + 1);
            g00 = S[a0 + s0]      * (vy0 * vx0);
            g01 = S[a0 + s1]      * (vy0 * vx1);
            g10 = S[a0 + LW + s0] * (vy1 * vx0);
            g11 = S[a0 + LW + s1] * (vy1 * vx1);
        } else {
            // out-of-halo fallback (never taken for N(0,1) flow): global
            int x0c = min(max(x0, 0), W - 1);
            int x1c = min(max(x1, 0), W - 1);
            int y0c = min(max(y0, 0), H - 1);
            int y1c = min(max(y1, 0), H - 1);
            g00 = I1b[y0c * W + x0c] * (vy0 * vx0);
            g01 = I1b[y0c * W + x1c] * (vy0 * vx1);
            g10 = I1b[y1c * W + x0c] * (vy1 * vx0);
            g11 = I1b[y1c * W + x1c] * (vy1 * vx1);
        }

        float warped = g00 * (wy0 * wx0)
                     + g01 * (wy0 * wx1)
                     + g10 * (wy1 * wx0)
                     + g11 * (wy1 * wx1);

        float dataTerm = warped - i2[i];
        ru[i] = uu[i] - ALPHA * dataTerm * gy4[i];
        rv[i] = vv[i] - ALPHA * dataTerm * gx4[i];
    }

    f32x4 ruv = { ru[0], ru[1], ru[2], ru[3] };
    f32x4 rvv = { rv[0], rv[1], rv[2], rv[3] };
    __builtin_nontemporal_store(ruv, (f32x4*)(out_u + p));
    __builtin_nontemporal_store(rvv, (f32x4*)(out_v + p));
}

extern "C" void kernel_launch(void* const* d_in, const int* in_sizes, int n_in,
                              void* d_out, int out_size, void* d_ws, size_t ws_size,
                              hipStream_t stream) {
    const float* I1 = (const float*)d_in[0];
    const float* I2 = (const float*)d_in[1];
    const float* u  = (const float*)d_in[2];
    const float* v  = (const float*)d_in[3];

    int total = in_sizes[0];               // B*H*W = 16 * 1024 * 1024
    float* out_u = (float*)d_out;
    float* out_v = (float*)d_out + total;

    dim3 grid(IMG_W / TW, IMG_H / TH, total / (IMG_H * IMG_W));
    dataterm_kernel<<<grid, dim3(256), 0, stream>>>(I1, I2, u, v, out_u, out_v);
}